// Round 1
// baseline (823.936 us; speedup 1.0000x reference)
//
#include <hip/hip_runtime.h>
#include <math.h>

#define B_N    8192
#define D_DIM  192
#define C_CLS  1024
#define MARGIN 0.2f
#define EPS_T  1e-6f

#define TI     64
#define TJ     64
#define KC     48
#define PAD_A  196   // 196%32=4 -> row r bank start 4r; rows ti+16*ri -> 2-way max (free)
#define PAD_B  52    // 52%32=20 -> rows tj+16*rj -> starts {0,20,8,28} distinct
#define JSPLIT 4
#define JLEN   (B_N / JSPLIT)

__device__ __forceinline__ unsigned fkey(float f) {
  unsigned u = __float_as_uint(f);
  return (u & 0x80000000u) ? ~u : (u | 0x80000000u);
}

// ---------------- sq[i] = ||e_i||^2 ----------------
__global__ __launch_bounds__(256) void sq_kernel(const float* __restrict__ e,
                                                 float* __restrict__ sq) {
  int w = threadIdx.x >> 6, lane = threadIdx.x & 63;
  int row = blockIdx.x * 4 + w;
  const float* p = e + (size_t)row * D_DIM;
  float v0 = p[lane], v1 = p[lane + 64], v2 = p[lane + 128];
  float s = v0 * v0 + v1 * v1 + v2 * v2;
  #pragma unroll
  for (int off = 32; off; off >>= 1) s += __shfl_xor(s, off);
  if (lane == 0) sq[row] = s;
}

// ---------------- hard mining ----------------
// per anchor i: max over same-class (j!=i) and min over diff-class of
// val = sq_j - 2*dot(e_i,e_j)   (monotone proxy for dist)
__global__ __launch_bounds__(256) void mine_kernel(
    const float* __restrict__ e, const int* __restrict__ tgt,
    const float* __restrict__ sq,
    unsigned long long* __restrict__ posw, unsigned long long* __restrict__ negw) {
  __shared__ float lds_a[TI * PAD_A];      // 50176 B
  __shared__ float lds_b[TJ * PAD_B];      // 13312 B
  __shared__ int   lds_t[TJ];
  __shared__ float lds_s[TJ];
  __shared__ unsigned long long lds_pos[TI];
  __shared__ unsigned long long lds_neg[TI];

  const int tid = threadIdx.x;
  const int i0 = blockIdx.x * TI;
  const int j_begin = blockIdx.y * JLEN;

  // stage A tile (rows i0..i0+63 are one contiguous 48KB span)
  {
    const float4* src = (const float4*)(e + (size_t)i0 * D_DIM);
    #pragma unroll
    for (int t = 0; t < 12; ++t) {
      int f = t * 256 + tid;          // float4 index 0..3071
      int r = f / 48;
      int c = (f - r * 48) * 4;
      *(float4*)&lds_a[r * PAD_A + c] = src[f];
    }
  }
  if (tid < TI) { lds_pos[tid] = 0ULL; lds_neg[tid] = ~0ULL; }

  const int ti = tid & 15;
  const int tj = tid >> 4;

  int   my_i[4], my_t[4];
  float pv[4], nv[4];
  unsigned pi_[4], ni_[4];
  #pragma unroll
  for (int r = 0; r < 4; ++r) {
    my_i[r] = i0 + ti + 16 * r;
    my_t[r] = tgt[my_i[r]];
    pv[r] = -3.4e38f; nv[r] = 3.4e38f;
    pi_[r] = 0xFFFFFFFFu; ni_[r] = 0xFFFFFFFFu;
  }

  for (int j0 = j_begin; j0 < j_begin + JLEN; j0 += TJ) {
    float acc[4][4];
    #pragma unroll
    for (int a = 0; a < 4; ++a)
      #pragma unroll
      for (int b = 0; b < 4; ++b) acc[a][b] = 0.f;

    for (int kc = 0; kc < D_DIM; kc += KC) {
      __syncthreads();
      // stage B chunk: 64 rows x 48 floats = 768 float4
      #pragma unroll
      for (int t = 0; t < 3; ++t) {
        int ff = t * 256 + tid;
        int r = ff / 12;
        int c4 = ff - r * 12;
        float4 v = *(const float4*)(e + (size_t)(j0 + r) * D_DIM + kc + c4 * 4);
        *(float4*)&lds_b[r * PAD_B + c4 * 4] = v;
      }
      if (kc == 0 && tid < TJ) {
        lds_t[tid] = tgt[j0 + tid];
        lds_s[tid] = sq[j0 + tid];
      }
      __syncthreads();
      #pragma unroll
      for (int kq = 0; kq < KC; kq += 4) {
        float4 a4[4], b4[4];
        #pragma unroll
        for (int r = 0; r < 4; ++r)
          a4[r] = *(const float4*)&lds_a[(ti + 16 * r) * PAD_A + kc + kq];
        #pragma unroll
        for (int r = 0; r < 4; ++r)
          b4[r] = *(const float4*)&lds_b[(tj + 16 * r) * PAD_B + kq];
        #pragma unroll
        for (int a = 0; a < 4; ++a)
          #pragma unroll
          for (int b = 0; b < 4; ++b) {
            acc[a][b] += a4[a].x * b4[b].x + a4[a].y * b4[b].y
                       + a4[a].z * b4[b].z + a4[a].w * b4[b].w;
          }
      }
    }
    // epilogue: update running bests (reads lds_t/lds_s staged at kc==0;
    // next overwrite is after the next loop-top barrier)
    #pragma unroll
    for (int b = 0; b < 4; ++b) {
      int jl = tj + 16 * b;
      int jg = j0 + jl;
      int tc = lds_t[jl];
      float s = lds_s[jl];
      #pragma unroll
      for (int a = 0; a < 4; ++a) {
        float val = s - 2.f * acc[a][b];
        if (tc == my_t[a]) {
          if (jg != my_i[a] && val > pv[a]) { pv[a] = val; pi_[a] = (unsigned)jg; }
        } else {
          if (val < nv[a]) { nv[a] = val; ni_[a] = (unsigned)jg; }
        }
      }
    }
  }

  // merge into LDS (packed key|idx; pos uses ~idx so ties pick smallest idx)
  #pragma unroll
  for (int r = 0; r < 4; ++r) {
    int il = ti + 16 * r;
    if (pi_[r] != 0xFFFFFFFFu)
      atomicMax(&lds_pos[il],
                ((unsigned long long)fkey(pv[r]) << 32) |
                (unsigned long long)(unsigned)(~pi_[r]));
    if (ni_[r] != 0xFFFFFFFFu)
      atomicMin(&lds_neg[il],
                ((unsigned long long)fkey(nv[r]) << 32) |
                (unsigned long long)ni_[r]);
  }
  __syncthreads();
  if (tid < TI) {
    atomicMax(&posw[i0 + tid], lds_pos[tid]);
    atomicMin(&negw[i0 + tid], lds_neg[tid]);
  }
}

// ---------------- cross entropy ----------------
__global__ __launch_bounds__(1024) void ce_kernel(const float* __restrict__ logits,
                                                  const int* __restrict__ tgt,
                                                  float* __restrict__ accum) {
  __shared__ float part[16];
  int w = threadIdx.x >> 6, lane = threadIdx.x & 63;
  int row = blockIdx.x * 16 + w;
  const float* p = logits + (size_t)row * C_CLS;
  float4 x[4];
  #pragma unroll
  for (int t = 0; t < 4; ++t) x[t] = *(const float4*)(p + lane * 4 + 256 * t);
  float m = -3.4e38f;
  #pragma unroll
  for (int t = 0; t < 4; ++t)
    m = fmaxf(m, fmaxf(fmaxf(x[t].x, x[t].y), fmaxf(x[t].z, x[t].w)));
  #pragma unroll
  for (int off = 32; off; off >>= 1) m = fmaxf(m, __shfl_xor(m, off));
  float s = 0.f;
  #pragma unroll
  for (int t = 0; t < 4; ++t)
    s += __expf(x[t].x - m) + __expf(x[t].y - m) +
         __expf(x[t].z - m) + __expf(x[t].w - m);
  #pragma unroll
  for (int off = 32; off; off >>= 1) s += __shfl_xor(s, off);
  if (lane == 0) part[w] = m + __logf(s) - p[tgt[row]];
  __syncthreads();
  if (threadIdx.x == 0) {
    float t = 0.f;
    #pragma unroll
    for (int i = 0; i < 16; ++i) t += part[i];
    atomicAdd(accum, t);
  }
}

// ---------------- triplet loss on mined indices ----------------
__global__ __launch_bounds__(1024) void trip_kernel(
    const float* __restrict__ e,
    const unsigned long long* __restrict__ posw,
    const unsigned long long* __restrict__ negw,
    float* __restrict__ accum) {
  __shared__ float ssum[16];
  __shared__ float scnt[16];
  int w = threadIdx.x >> 6, lane = threadIdx.x & 63;
  int i = blockIdx.x * 16 + w;
  unsigned long long pp = posw[i], np = negw[i];
  float res = 0.f, c = 0.f;
  if (pp != 0ULL && np != ~0ULL) {
    unsigned pidx = ~(unsigned)pp;
    unsigned nidx = (unsigned)np;
    const float* pa = e + (size_t)i * D_DIM;
    const float* pb = e + (size_t)pidx * D_DIM;
    const float* pc = e + (size_t)nidx * D_DIM;
    float dap = 0.f, dan = 0.f;
    #pragma unroll
    for (int t = 0; t < 3; ++t) {
      int k = lane + 64 * t;
      float av = pa[k];
      float d1 = av - pb[k] + EPS_T;
      float d2 = av - pc[k] + EPS_T;
      dap += d1 * d1;
      dan += d2 * d2;
    }
    #pragma unroll
    for (int off = 32; off; off >>= 1) {
      dap += __shfl_xor(dap, off);
      dan += __shfl_xor(dan, off);
    }
    res = fmaxf(sqrtf(dap) - sqrtf(dan) + MARGIN, 0.f);
    c = 1.f;
  }
  if (lane == 0) { ssum[w] = res; scnt[w] = c; }
  __syncthreads();
  if (threadIdx.x == 0) {
    float a = 0.f, b = 0.f;
    #pragma unroll
    for (int k = 0; k < 16; ++k) { a += ssum[k]; b += scnt[k]; }
    atomicAdd(&accum[1], a);
    atomicAdd(&accum[2], b);
  }
}

// ---------------- finalize ----------------
__global__ void fin_kernel(const float* __restrict__ accum, float* __restrict__ out) {
  float cls = accum[0] / (float)B_N;
  float ts = accum[1], tc = accum[2];
  float trip = (tc > 0.f) ? ts / fmaxf(tc, 1.f) : 0.f;
  out[0] = cls + trip;
}

extern "C" void kernel_launch(void* const* d_in, const int* in_sizes, int n_in,
                              void* d_out, int out_size, void* d_ws, size_t ws_size,
                              hipStream_t stream) {
  const float* emb    = (const float*)d_in[0];
  const float* logits = (const float*)d_in[1];
  const int*   tgt    = (const int*)d_in[2];
  float* out = (float*)d_out;

  char* ws = (char*)d_ws;
  unsigned long long* posw = (unsigned long long*)ws;            // 65536 B
  unsigned long long* negw = (unsigned long long*)(ws + 65536);  // 65536 B
  float* sq    = (float*)(ws + 131072);                          // 32768 B
  float* accum = (float*)(ws + 163840);                          // 16 B: cls,tsum,tcnt

  hipMemsetAsync(posw, 0, 65536, stream);
  hipMemsetAsync(negw, 0xFF, 65536, stream);
  hipMemsetAsync(accum, 0, 16, stream);

  sq_kernel<<<2048, 256, 0, stream>>>(emb, sq);
  mine_kernel<<<dim3(B_N / TI, JSPLIT), 256, 0, stream>>>(emb, tgt, sq, posw, negw);
  ce_kernel<<<512, 1024, 0, stream>>>(logits, tgt, accum);
  trip_kernel<<<512, 1024, 0, stream>>>(emb, posw, negw, accum);
  fin_kernel<<<1, 1, 0, stream>>>(accum, out);
}

// Round 2
// 174.557 us; speedup vs baseline: 4.7202x; 4.7202x over previous
//
#include <hip/hip_runtime.h>
#include <math.h>

#define B_N    8192
#define D_DIM  192
#define C_CLS  1024
#define MARGIN 0.2f
#define EPS_T  1e-6f

#define TI     128
#define TJ     128
#define JSPLIT 8
#define JLEN   (B_N / JSPLIT)   // 1024
#define LDB    200              // LDS B row stride in bf16 (400 B: 16B-aligned, 2-way banks = free)

typedef __attribute__((ext_vector_type(8))) short v8s;
typedef __attribute__((ext_vector_type(4))) float v4f;
typedef __attribute__((ext_vector_type(4))) int   v4i;

__device__ __forceinline__ unsigned fkey(float f) {
  unsigned u = __float_as_uint(f);
  return (u & 0x80000000u) ? ~u : (u | 0x80000000u);
}

// ---------------- fp32 -> bf16 (RTNE) ----------------
__device__ __forceinline__ unsigned short to_bf(float x) {
  unsigned u = __float_as_uint(x);
  u += 0x7fffu + ((u >> 16) & 1u);
  return (unsigned short)(u >> 16);
}

__global__ __launch_bounds__(256) void cvt_kernel(const float* __restrict__ e,
                                                  unsigned short* __restrict__ ebf) {
  int t = blockIdx.x * 256 + threadIdx.x;      // 393216 float4 groups
  float4 v = ((const float4*)e)[t];
  ushort4 o;
  o.x = to_bf(v.x); o.y = to_bf(v.y); o.z = to_bf(v.z); o.w = to_bf(v.w);
  ((ushort4*)ebf)[t] = o;
}

// ---------------- sq[i] = ||e_i||^2 (fp32) ----------------
__global__ __launch_bounds__(256) void sq_kernel(const float* __restrict__ e,
                                                 float* __restrict__ sq) {
  int w = threadIdx.x >> 6, lane = threadIdx.x & 63;
  int row = blockIdx.x * 4 + w;
  const float* p = e + (size_t)row * D_DIM;
  float v0 = p[lane], v1 = p[lane + 64], v2 = p[lane + 128];
  float s = v0 * v0 + v1 * v1 + v2 * v2;
  #pragma unroll
  for (int off = 32; off; off >>= 1) s += __shfl_xor(s, off);
  if (lane == 0) sq[row] = s;
}

// ---------------- hard mining via bf16 MFMA ----------------
// per anchor i: argmax over same-class (self allowed; self-win => invalid) and
// argmin over diff-class of val = sq_j - 2*dot_bf16(e_i,e_j)
__global__ __launch_bounds__(256, 2) void mine_kernel(
    const unsigned short* __restrict__ ebf, const int* __restrict__ tgt,
    const float* __restrict__ sq,
    unsigned long long* __restrict__ posw, unsigned long long* __restrict__ negw) {
  __shared__ unsigned short lds_b[TJ * LDB];   // 51200 B
  __shared__ int   lds_t[TJ];
  __shared__ float lds_s[TJ];

  const int tid  = threadIdx.x;
  const int w    = tid >> 6;
  const int lane = tid & 63;
  const int ln15 = lane & 15;
  const int quad = lane >> 4;
  const int i0      = blockIdx.x * TI;
  const int j_begin = blockIdx.y * JLEN;

  // output rows per lane: i0 + w*32 + ra*16 + quad*4 + r   (C/D layout)
  int my_t[2][4];
  {
    const int base = i0 + w * 32 + quad * 4;
    v4i t0 = *(const v4i*)&tgt[base];
    v4i t1 = *(const v4i*)&tgt[base + 16];
    my_t[0][0] = t0.x; my_t[0][1] = t0.y; my_t[0][2] = t0.z; my_t[0][3] = t0.w;
    my_t[1][0] = t1.x; my_t[1][1] = t1.y; my_t[1][2] = t1.z; my_t[1][3] = t1.w;
  }

  // A fragments held in registers: input rows i0 + w*32 + ra*16 + ln15 (A layout)
  v8s afrag[2][6];
  #pragma unroll
  for (int ra = 0; ra < 2; ++ra) {
    const unsigned short* ap =
        ebf + (size_t)(i0 + w * 32 + ra * 16 + ln15) * D_DIM + quad * 8;
    #pragma unroll
    for (int ks = 0; ks < 6; ++ks)
      afrag[ra][ks] = *(const v8s*)(ap + ks * 32);
  }

  float    pv[2][4], nv[2][4];
  unsigned pi_[2][4], ni_[2][4];
  #pragma unroll
  for (int ra = 0; ra < 2; ++ra)
    #pragma unroll
    for (int r = 0; r < 4; ++r) {
      pv[ra][r] = -3.4e38f; nv[ra][r] = 3.4e38f;
      pi_[ra][r] = 0u; ni_[ra][r] = 0xFFFFFFFFu;
    }

  for (int j0 = j_begin; j0 < j_begin + JLEN; j0 += TJ) {
    __syncthreads();   // previous epilogue done before restage
    // stage B tile: 128 rows x 192 bf16 = 3072 16B chunks, 12 per thread
    #pragma unroll
    for (int t = 0; t < 12; ++t) {
      int c = t * 256 + tid;
      int row = c / 24;
      int off = c - row * 24;   // 16B units
      v8s v = *(const v8s*)(ebf + (size_t)(j0 + row) * D_DIM + off * 8);
      *(v8s*)&lds_b[row * LDB + off * 8] = v;
    }
    if (tid < TJ) { lds_t[tid] = tgt[j0 + tid]; lds_s[tid] = sq[j0 + tid]; }
    __syncthreads();

    v4f acc[2][8];
    #pragma unroll
    for (int ra = 0; ra < 2; ++ra)
      #pragma unroll
      for (int tb = 0; tb < 8; ++tb)
        acc[ra][tb] = (v4f){0.f, 0.f, 0.f, 0.f};

    #pragma unroll
    for (int ks = 0; ks < 6; ++ks) {
      v8s bfr[8];
      #pragma unroll
      for (int tb = 0; tb < 8; ++tb)
        bfr[tb] = *(const v8s*)&lds_b[(tb * 16 + ln15) * LDB + ks * 32 + quad * 8];
      #pragma unroll
      for (int ra = 0; ra < 2; ++ra)
        #pragma unroll
        for (int tb = 0; tb < 8; ++tb)
          acc[ra][tb] = __builtin_amdgcn_mfma_f32_16x16x32_bf16(
              afrag[ra][ks], bfr[tb], acc[ra][tb], 0, 0, 0);
    }

    // epilogue: update running bests
    #pragma unroll
    for (int tb = 0; tb < 8; ++tb) {
      int jl = tb * 16 + ln15;
      int jg = j0 + jl;
      int tc = lds_t[jl];
      float s = lds_s[jl];
      #pragma unroll
      for (int ra = 0; ra < 2; ++ra)
        #pragma unroll
        for (int r = 0; r < 4; ++r) {
          float val  = fmaf(acc[ra][tb][r], -2.0f, s);
          bool  same = (tc == my_t[ra][r]);
          float vp = same ? val : -3.4e38f;
          float vn = same ? 3.4e38f : val;
          if (vp > pv[ra][r]) { pv[ra][r] = vp; pi_[ra][r] = (unsigned)jg; }
          if (vn < nv[ra][r]) { nv[ra][r] = vn; ni_[ra][r] = (unsigned)jg; }
        }
    }
  }

  // cross-lane reduce (16 lanes share an output row) + global merge
  #pragma unroll
  for (int ra = 0; ra < 2; ++ra)
    #pragma unroll
    for (int r = 0; r < 4; ++r) {
      unsigned long long pk =
          ((unsigned long long)fkey(pv[ra][r]) << 32) |
          (unsigned long long)(unsigned)(~pi_[ra][r]);
      unsigned long long nk =
          ((unsigned long long)fkey(nv[ra][r]) << 32) |
          (unsigned long long)ni_[ra][r];
      #pragma unroll
      for (int off = 1; off < 16; off <<= 1) {
        unsigned long long po = __shfl_xor(pk, off);
        unsigned long long no = __shfl_xor(nk, off);
        pk = pk > po ? pk : po;
        nk = nk < no ? nk : no;
      }
      if (ln15 == 0) {
        int row = i0 + w * 32 + ra * 16 + quad * 4 + r;
        atomicMax(&posw[row], pk);
        atomicMin(&negw[row], nk);
      }
    }
}

// ---------------- cross entropy ----------------
__global__ __launch_bounds__(1024) void ce_kernel(const float* __restrict__ logits,
                                                  const int* __restrict__ tgt,
                                                  float* __restrict__ accum) {
  __shared__ float part[16];
  int w = threadIdx.x >> 6, lane = threadIdx.x & 63;
  int row = blockIdx.x * 16 + w;
  const float* p = logits + (size_t)row * C_CLS;
  float4 x[4];
  #pragma unroll
  for (int t = 0; t < 4; ++t) x[t] = *(const float4*)(p + lane * 4 + 256 * t);
  float m = -3.4e38f;
  #pragma unroll
  for (int t = 0; t < 4; ++t)
    m = fmaxf(m, fmaxf(fmaxf(x[t].x, x[t].y), fmaxf(x[t].z, x[t].w)));
  #pragma unroll
  for (int off = 32; off; off >>= 1) m = fmaxf(m, __shfl_xor(m, off));
  float s = 0.f;
  #pragma unroll
  for (int t = 0; t < 4; ++t)
    s += __expf(x[t].x - m) + __expf(x[t].y - m) +
         __expf(x[t].z - m) + __expf(x[t].w - m);
  #pragma unroll
  for (int off = 32; off; off >>= 1) s += __shfl_xor(s, off);
  if (lane == 0) part[w] = m + __logf(s) - p[tgt[row]];
  __syncthreads();
  if (threadIdx.x == 0) {
    float t = 0.f;
    #pragma unroll
    for (int i = 0; i < 16; ++i) t += part[i];
    atomicAdd(accum, t);
  }
}

// ---------------- triplet loss on mined indices (exact fp32) ----------------
__global__ __launch_bounds__(1024) void trip_kernel(
    const float* __restrict__ e,
    const unsigned long long* __restrict__ posw,
    const unsigned long long* __restrict__ negw,
    float* __restrict__ accum) {
  __shared__ float ssum[16];
  __shared__ float scnt[16];
  int w = threadIdx.x >> 6, lane = threadIdx.x & 63;
  int i = blockIdx.x * 16 + w;
  unsigned long long pp = posw[i], np = negw[i];
  unsigned pidx = ~(unsigned)pp;
  unsigned nidx = (unsigned)np;
  float res = 0.f, c = 0.f;
  // pidx == i means self won the argmax => no real positive => invalid row
  if (pp != 0ULL && np != ~0ULL && pidx != (unsigned)i) {
    const float* pa = e + (size_t)i * D_DIM;
    const float* pb = e + (size_t)pidx * D_DIM;
    const float* pc = e + (size_t)nidx * D_DIM;
    float dap = 0.f, dan = 0.f;
    #pragma unroll
    for (int t = 0; t < 3; ++t) {
      int k = lane + 64 * t;
      float av = pa[k];
      float d1 = av - pb[k] + EPS_T;
      float d2 = av - pc[k] + EPS_T;
      dap += d1 * d1;
      dan += d2 * d2;
    }
    #pragma unroll
    for (int off = 32; off; off >>= 1) {
      dap += __shfl_xor(dap, off);
      dan += __shfl_xor(dan, off);
    }
    res = fmaxf(sqrtf(dap) - sqrtf(dan) + MARGIN, 0.f);
    c = 1.f;
  }
  if (lane == 0) { ssum[w] = res; scnt[w] = c; }
  __syncthreads();
  if (threadIdx.x == 0) {
    float a = 0.f, b = 0.f;
    #pragma unroll
    for (int k = 0; k < 16; ++k) { a += ssum[k]; b += scnt[k]; }
    atomicAdd(&accum[1], a);
    atomicAdd(&accum[2], b);
  }
}

// ---------------- finalize ----------------
__global__ void fin_kernel(const float* __restrict__ accum, float* __restrict__ out) {
  float cls = accum[0] / (float)B_N;
  float ts = accum[1], tc = accum[2];
  float trip = (tc > 0.f) ? ts / fmaxf(tc, 1.f) : 0.f;
  out[0] = cls + trip;
}

extern "C" void kernel_launch(void* const* d_in, const int* in_sizes, int n_in,
                              void* d_out, int out_size, void* d_ws, size_t ws_size,
                              hipStream_t stream) {
  const float* emb    = (const float*)d_in[0];
  const float* logits = (const float*)d_in[1];
  const int*   tgt    = (const int*)d_in[2];
  float* out = (float*)d_out;

  char* ws = (char*)d_ws;
  unsigned short* ebf = (unsigned short*)ws;                          // 3,145,728 B
  unsigned long long* posw = (unsigned long long*)(ws + 3145728);     // 65536 B
  unsigned long long* negw = (unsigned long long*)(ws + 3145728 + 65536);
  float* sq    = (float*)(ws + 3145728 + 131072);                     // 32768 B
  float* accum = (float*)(ws + 3145728 + 163840);                     // 16 B

  hipMemsetAsync(posw, 0, 65536, stream);
  hipMemsetAsync(negw, 0xFF, 65536, stream);
  hipMemsetAsync(accum, 0, 16, stream);

  cvt_kernel<<<1536, 256, 0, stream>>>(emb, ebf);
  sq_kernel<<<2048, 256, 0, stream>>>(emb, sq);
  mine_kernel<<<dim3(B_N / TI, JSPLIT), 256, 0, stream>>>(ebf, tgt, sq, posw, negw);
  ce_kernel<<<512, 1024, 0, stream>>>(logits, tgt, accum);
  trip_kernel<<<512, 1024, 0, stream>>>(emb, posw, negw, accum);
  fin_kernel<<<1, 1, 0, stream>>>(accum, out);
}

// Round 3
// 145.646 us; speedup vs baseline: 5.6571x; 1.1985x over previous
//
#include <hip/hip_runtime.h>
#include <math.h>

#define B_N    8192
#define D_DIM  192
#define C_CLS  1024
#define MARGIN 0.2f
#define EPS_T  1e-6f

#define TI     128
#define TJ     128
#define JSPLIT 8
#define JLEN   (B_N / JSPLIT)   // 1024
#define LDB    200              // LDS row stride in bf16 (400 B: 16B-aligned, good bank spread)

typedef short v8s  __attribute__((ext_vector_type(8)));
typedef float v16f __attribute__((ext_vector_type(16)));

__device__ __forceinline__ unsigned fkey(float f) {
  unsigned u = __float_as_uint(f);
  return (u & 0x80000000u) ? ~u : (u | 0x80000000u);
}

__device__ __forceinline__ unsigned short to_bf(float x) {
  unsigned u = __float_as_uint(x);
  u += 0x7fffu + ((u >> 16) & 1u);
  return (unsigned short)(u >> 16);
}

// ---------------- prep: cvt fp32->bf16, sq = ||e||^2, init ws ----------------
__global__ __launch_bounds__(256) void prep_kernel(
    const float* __restrict__ e, unsigned short* __restrict__ ebf,
    float* __restrict__ sq,
    unsigned long long* __restrict__ posw, unsigned long long* __restrict__ negw,
    float* __restrict__ accum) {
  int w = threadIdx.x >> 6, lane = threadIdx.x & 63;
  int row = blockIdx.x * 4 + w;
  const float* p = e + (size_t)row * D_DIM;
  float v0 = p[lane], v1 = p[lane + 64], v2 = p[lane + 128];
  unsigned short* q = ebf + (size_t)row * D_DIM;
  q[lane] = to_bf(v0); q[lane + 64] = to_bf(v1); q[lane + 128] = to_bf(v2);
  float s = v0 * v0 + v1 * v1 + v2 * v2;
  #pragma unroll
  for (int off = 32; off; off >>= 1) s += __shfl_xor(s, off);
  if (lane == 0) sq[row] = s;
  int b = blockIdx.x;
  if (b < 32)       posw[b * 256 + threadIdx.x] = 0ULL;
  else if (b < 64)  negw[(b - 32) * 256 + threadIdx.x] = ~0ULL;
  else if (b == 64 && threadIdx.x < 4) ((unsigned*)accum)[threadIdx.x] = 0u;
}

// ---------------- hard mining (j=M from LDS, i=N in regs) + fused CE ----------------
__global__ __launch_bounds__(256, 2) void mine_kernel(
    const unsigned short* __restrict__ ebf, const int* __restrict__ tgt,
    const float* __restrict__ sq, const float* __restrict__ logits,
    unsigned long long* __restrict__ posw, unsigned long long* __restrict__ negw,
    float* __restrict__ accum) {
  __shared__ unsigned short lds_b[TJ * LDB];   // 51200 B
  __shared__ int   lds_t[TJ];
  __shared__ float lds_s[TJ];
  __shared__ float ce_part[4];

  const int tid  = threadIdx.x;
  const int w    = tid >> 6;
  const int lane = tid & 63;
  const int n5   = lane & 31;
  const int h    = lane >> 5;
  const int wj   = w & 1;     // j band (M side)
  const int wi   = w >> 1;    // i band (N side)
  const int i0 = blockIdx.x * TI;
  const int jb = blockIdx.y * JLEN;

  // ---- stage this block's i-rows through LDS (coalesced), pull B-frags to regs ----
  {
    const unsigned short* src = ebf + (size_t)i0 * D_DIM;
    #pragma unroll
    for (int t = 0; t < 12; ++t) {
      int c = t * 256 + tid;
      int row = c / 24;
      int off = c - row * 24;
      *(v8s*)&lds_b[row * LDB + off * 8] = *(const v8s*)(src + (size_t)row * D_DIM + off * 8);
    }
  }
  __syncthreads();
  v8s bfrag[2][12];
  #pragma unroll
  for (int tb = 0; tb < 2; ++tb)
    #pragma unroll
    for (int kc = 0; kc < 12; ++kc)
      bfrag[tb][kc] = *(const v8s*)&lds_b[(wi * 64 + tb * 32 + n5) * LDB + kc * 16 + h * 8];

  int my_t[2];
  #pragma unroll
  for (int tb = 0; tb < 2; ++tb) my_t[tb] = tgt[i0 + wi * 64 + tb * 32 + n5];

  float    pv[2] = {-3.4e38f, -3.4e38f}, nv[2] = {3.4e38f, 3.4e38f};
  unsigned pi_[2] = {0u, 0u}, ni_[2] = {0xFFFFFFFFu, 0xFFFFFFFFu};

  for (int j0 = jb; j0 < jb + JLEN; j0 += TJ) {
    __syncthreads();
    // stage j-rows (M side)
    #pragma unroll
    for (int t = 0; t < 12; ++t) {
      int c = t * 256 + tid;
      int row = c / 24;
      int off = c - row * 24;
      *(v8s*)&lds_b[row * LDB + off * 8] =
          *(const v8s*)(ebf + (size_t)(j0 + row) * D_DIM + off * 8);
    }
    if (tid < TJ) { lds_t[tid] = tgt[j0 + tid]; lds_s[tid] = sq[j0 + tid]; }
    __syncthreads();

    v16f acc[2][2];
    #pragma unroll
    for (int ta = 0; ta < 2; ++ta)
      #pragma unroll
      for (int tb = 0; tb < 2; ++tb)
        #pragma unroll
        for (int r = 0; r < 16; ++r) acc[ta][tb][r] = 0.f;

    #pragma unroll
    for (int kc = 0; kc < 12; ++kc) {
      v8s afr0 = *(const v8s*)&lds_b[(wj * 64 +  0 + n5) * LDB + kc * 16 + h * 8];
      v8s afr1 = *(const v8s*)&lds_b[(wj * 64 + 32 + n5) * LDB + kc * 16 + h * 8];
      acc[0][0] = __builtin_amdgcn_mfma_f32_32x32x16_bf16(afr0, bfrag[0][kc], acc[0][0], 0, 0, 0);
      acc[0][1] = __builtin_amdgcn_mfma_f32_32x32x16_bf16(afr0, bfrag[1][kc], acc[0][1], 0, 0, 0);
      acc[1][0] = __builtin_amdgcn_mfma_f32_32x32x16_bf16(afr1, bfrag[0][kc], acc[1][0], 0, 0, 0);
      acc[1][1] = __builtin_amdgcn_mfma_f32_32x32x16_bf16(afr1, bfrag[1][kc], acc[1][1], 0, 0, 0);
    }

    // epilogue: rows decode as j = ta*32 + q + 8p + 4h (+wj*64); col = i = lane&31
    #pragma unroll
    for (int ta = 0; ta < 2; ++ta)
      #pragma unroll
      for (int p = 0; p < 4; ++p) {
        int jb4 = wj * 64 + ta * 32 + p * 8 + h * 4;
        float4 s4 = *(const float4*)&lds_s[jb4];   // broadcast (2 uniq addrs/wave)
        int4   t4 = *(const int4*)&lds_t[jb4];
        #pragma unroll
        for (int q = 0; q < 3 + 1; ++q) {
          float sv = (q == 0) ? s4.x : (q == 1) ? s4.y : (q == 2) ? s4.z : s4.w;
          int   tv = (q == 0) ? t4.x : (q == 1) ? t4.y : (q == 2) ? t4.z : t4.w;
          unsigned jg = (unsigned)(j0 + jb4 + q);
          #pragma unroll
          for (int tb = 0; tb < 2; ++tb) {
            float val = fmaf(acc[ta][tb][p * 4 + q], -2.0f, sv);
            bool same = (tv == my_t[tb]);
            float vp = same ? val : -3.4e38f;
            float vn = same ? 3.4e38f : val;
            if (vp > pv[tb]) { pv[tb] = vp; pi_[tb] = jg; }
            if (vn < nv[tb]) { nv[tb] = vn; ni_[tb] = jg; }
          }
        }
      }
  }

  // ---- merge: h-partner lanes (same i col), then global packed atomics ----
  #pragma unroll
  for (int tb = 0; tb < 2; ++tb) {
    unsigned long long pk =
        ((unsigned long long)fkey(pv[tb]) << 32) | (unsigned long long)(unsigned)(~pi_[tb]);
    unsigned long long nk =
        ((unsigned long long)fkey(nv[tb]) << 32) | (unsigned long long)ni_[tb];
    unsigned long long po = __shfl_xor(pk, 32);
    unsigned long long no = __shfl_xor(nk, 32);
    pk = pk > po ? pk : po;
    nk = nk < no ? nk : no;
    if (h == 0) {
      int irow = i0 + wi * 64 + tb * 32 + n5;
      atomicMax(&posw[irow], pk);
      atomicMin(&negw[irow], nk);
    }
  }

  // ---- fused cross-entropy: this block handles 16 logits rows ----
  int blin = blockIdx.y * 64 + blockIdx.x;
  float ce_acc = 0.f;
  #pragma unroll
  for (int it = 0; it < 4; ++it) {
    int row = blin * 16 + it * 4 + w;
    const float* lp = logits + (size_t)row * C_CLS;
    float4 x[4];
    #pragma unroll
    for (int t = 0; t < 4; ++t) x[t] = *(const float4*)(lp + lane * 4 + 256 * t);
    float m = -3.4e38f;
    #pragma unroll
    for (int t = 0; t < 4; ++t)
      m = fmaxf(m, fmaxf(fmaxf(x[t].x, x[t].y), fmaxf(x[t].z, x[t].w)));
    #pragma unroll
    for (int off = 32; off; off >>= 1) m = fmaxf(m, __shfl_xor(m, off));
    float s = 0.f;
    #pragma unroll
    for (int t = 0; t < 4; ++t)
      s += __expf(x[t].x - m) + __expf(x[t].y - m) +
           __expf(x[t].z - m) + __expf(x[t].w - m);
    #pragma unroll
    for (int off = 32; off; off >>= 1) s += __shfl_xor(s, off);
    if (lane == 0) ce_acc += m + __logf(s) - lp[tgt[row]];
  }
  if (lane == 0) ce_part[w] = ce_acc;
  __syncthreads();
  if (tid == 0)
    atomicAdd(&accum[0], ce_part[0] + ce_part[1] + ce_part[2] + ce_part[3]);
}

// ---------------- triplet loss on mined indices + last-block finalize ----------------
__global__ __launch_bounds__(1024) void trip_fin_kernel(
    const float* __restrict__ e,
    const unsigned long long* __restrict__ posw,
    const unsigned long long* __restrict__ negw,
    float* __restrict__ accum, float* __restrict__ out) {
  __shared__ float ssum[16];
  __shared__ float scnt[16];
  int w = threadIdx.x >> 6, lane = threadIdx.x & 63;
  int i = blockIdx.x * 16 + w;
  unsigned long long pp = posw[i], np = negw[i];
  unsigned pidx = ~(unsigned)pp;
  unsigned nidx = (unsigned)np;
  float res = 0.f, c = 0.f;
  // pidx == i means self won the argmax => no real positive => invalid row
  if (pp != 0ULL && np != ~0ULL && pidx != (unsigned)i) {
    const float* pa = e + (size_t)i * D_DIM;
    const float* pb = e + (size_t)pidx * D_DIM;
    const float* pc = e + (size_t)nidx * D_DIM;
    float dap = 0.f, dan = 0.f;
    #pragma unroll
    for (int t = 0; t < 3; ++t) {
      int k = lane + 64 * t;
      float av = pa[k];
      float d1 = av - pb[k] + EPS_T;
      float d2 = av - pc[k] + EPS_T;
      dap += d1 * d1;
      dan += d2 * d2;
    }
    #pragma unroll
    for (int off = 32; off; off >>= 1) {
      dap += __shfl_xor(dap, off);
      dan += __shfl_xor(dan, off);
    }
    res = fmaxf(sqrtf(dap) - sqrtf(dan) + MARGIN, 0.f);
    c = 1.f;
  }
  if (lane == 0) { ssum[w] = res; scnt[w] = c; }
  __syncthreads();
  if (threadIdx.x == 0) {
    float a = 0.f, b = 0.f;
    #pragma unroll
    for (int k = 0; k < 16; ++k) { a += ssum[k]; b += scnt[k]; }
    atomicAdd(&accum[1], a);
    atomicAdd(&accum[2], b);
    __threadfence();
    unsigned old = atomicAdd((unsigned*)&accum[3], 1u);
    if (old == 511u) {
      __threadfence();
      float cls = atomicAdd(&accum[0], 0.f);   // coherent reads via atomics
      float ts  = atomicAdd(&accum[1], 0.f);
      float tc  = atomicAdd(&accum[2], 0.f);
      float trip = (tc > 0.f) ? ts / fmaxf(tc, 1.f) : 0.f;
      out[0] = cls / (float)B_N + trip;
    }
  }
}

extern "C" void kernel_launch(void* const* d_in, const int* in_sizes, int n_in,
                              void* d_out, int out_size, void* d_ws, size_t ws_size,
                              hipStream_t stream) {
  const float* emb    = (const float*)d_in[0];
  const float* logits = (const float*)d_in[1];
  const int*   tgt    = (const int*)d_in[2];
  float* out = (float*)d_out;

  char* ws = (char*)d_ws;
  unsigned short* ebf = (unsigned short*)ws;                          // 3,145,728 B
  unsigned long long* posw = (unsigned long long*)(ws + 3145728);     // 65536 B
  unsigned long long* negw = (unsigned long long*)(ws + 3145728 + 65536);
  float* sq    = (float*)(ws + 3145728 + 131072);                     // 32768 B
  float* accum = (float*)(ws + 3145728 + 163840);                     // 16 B: cls,tsum,tcnt,counter

  prep_kernel<<<2048, 256, 0, stream>>>(emb, ebf, sq, posw, negw, accum);
  mine_kernel<<<dim3(B_N / TI, JSPLIT), 256, 0, stream>>>(ebf, tgt, sq, logits, posw, negw, accum);
  trip_fin_kernel<<<512, 1024, 0, stream>>>(emb, posw, negw, accum, out);
}